// Round 2
// baseline (530.216 us; speedup 1.0000x reference)
//
#include <hip/hip_runtime.h>

#define D_MODEL   2048
#define N_EXPERTS 64
#define TW        8            // tokens per wave
#define WAVES     4            // waves per block
#define TB        (TW * WAVES) // tokens per block = 32
#define THRESH    0.9f

__global__ __launch_bounds__(WAVES * 64, 2)
void dynk_kernel(const float* __restrict__ x,
                 const float* __restrict__ W,
                 const float* __restrict__ b,
                 float* __restrict__ out_rw,
                 float* __restrict__ out_probs,
                 float* __restrict__ out_cnt,
                 int n_tok)
{
    const int lane = threadIdx.x & 63;   // expert index
    const int wid  = threadIdx.x >> 6;
    const long tok0 = (long)blockIdx.x * TB + (long)wid * TW;
    if (tok0 >= n_tok) return;

    // ---- GEMM: logits[t][lane] = sum_k x[tok0+t][k] * W[k][lane] + b[lane]
    float acc[TW];
    const float bias = b[lane];
#pragma unroll
    for (int t = 0; t < TW; ++t) acc[t] = bias;

    const float* xp = x + tok0 * D_MODEL;

    for (int k0 = 0; k0 < D_MODEL; k0 += 8) {
        float w[8];
#pragma unroll
        for (int j = 0; j < 8; ++j)
            w[j] = W[(long)(k0 + j) * N_EXPERTS + lane];   // 64-lane coalesced, L2-hot
#pragma unroll
        for (int t = 0; t < TW; ++t) {
            const float4 xa = *reinterpret_cast<const float4*>(xp + (long)t * D_MODEL + k0);
            const float4 xb = *reinterpret_cast<const float4*>(xp + (long)t * D_MODEL + k0 + 4);
            acc[t] = fmaf(xa.x, w[0], acc[t]);
            acc[t] = fmaf(xa.y, w[1], acc[t]);
            acc[t] = fmaf(xa.z, w[2], acc[t]);
            acc[t] = fmaf(xa.w, w[3], acc[t]);
            acc[t] = fmaf(xb.x, w[4], acc[t]);
            acc[t] = fmaf(xb.y, w[5], acc[t]);
            acc[t] = fmaf(xb.z, w[6], acc[t]);
            acc[t] = fmaf(xb.w, w[7], acc[t]);
        }
    }

    // ---- per-token: softmax -> nucleus cutoff -> renormalize -> write
#pragma unroll 1
    for (int t = 0; t < TW; ++t) {
        const long tok = tok0 + t;
        const float l = acc[t];

        // softmax across the 64 lanes (experts)
        float m = l;
#pragma unroll
        for (int d = 32; d > 0; d >>= 1) m = fmaxf(m, __shfl_xor(m, d));
        const float e = expf(l - m);
        float s = e;
#pragma unroll
        for (int d = 32; d > 0; d >>= 1) s += __shfl_xor(s, d);
        const float p = e / s;

        // S = mass of experts ranked strictly before this lane
        // (descending prob, stable ties by original index)
        float S = 0.f;
#pragma unroll
        for (int j = 0; j < 64; ++j) {
            const float pj = __shfl(p, j);
            const bool before = (pj > p) || (pj == p && j < lane);
            S += before ? pj : 0.f;
        }
        const bool active = (S < THRESH);   // position 0 has S==0, always active

        float total = active ? p : 0.f;
#pragma unroll
        for (int d = 32; d > 0; d >>= 1) total += __shfl_xor(total, d);

        const unsigned long long msk = __ballot(active);
        const int cnt = __popcll(msk);
        const float wgt = active ? p / (total + 1e-6f) : 0.f;

        out_rw[tok * N_EXPERTS + lane]    = wgt;
        out_probs[tok * N_EXPERTS + lane] = p;
        if (lane == 0) out_cnt[tok] = (float)cnt;
    }
}

extern "C" void kernel_launch(void* const* d_in, const int* in_sizes, int n_in,
                              void* d_out, int out_size, void* d_ws, size_t ws_size,
                              hipStream_t stream) {
    const float* x = (const float*)d_in[0];
    const float* W = (const float*)d_in[1];
    const float* b = (const float*)d_in[2];
    const int n_tok = in_sizes[0] / D_MODEL;

    float* out      = (float*)d_out;
    float* rw       = out;
    float* probs    = out + (size_t)n_tok * N_EXPERTS;
    float* cnt      = out + 2 * (size_t)n_tok * N_EXPERTS;

    const int blocks = (n_tok + TB - 1) / TB;
    dynk_kernel<<<blocks, WAVES * 64, 0, stream>>>(x, W, b, rw, probs, cnt, n_tok);
}

// Round 4
// 239.800 us; speedup vs baseline: 2.2111x; 2.2111x over previous
//
#include <hip/hip_runtime.h>

#define D_MODEL   2048
#define N_EXPERTS 64
#define THRESH    0.9f

typedef __attribute__((ext_vector_type(8))) short bf16x8;
typedef __attribute__((ext_vector_type(4))) float f32x4;

union FragU { unsigned u[4]; bf16x8 v; };

// pack {top16(f0) low, top16(f1) high}
__device__ __forceinline__ unsigned pack_hi(float f0, float f1) {
    return __builtin_amdgcn_perm(__float_as_uint(f1), __float_as_uint(f0), 0x07060302u);
}
__device__ __forceinline__ float trunc_bf(float f) {
    return __uint_as_float(__float_as_uint(f) & 0xFFFF0000u);
}

// ---- prepack W [2048][64] fp32 -> EXACT 3-way bf16 split fragments in d_ws
// frag index: [ks=0..63][nt=0..3][lane], 4 u32 each (8 bf16 = k-elems q*8..q*8+7)
__global__ void prepack_w(const float* __restrict__ W,
                          bf16x8* __restrict__ c0, bf16x8* __restrict__ c1,
                          bf16x8* __restrict__ c2)
{
    const int ks = blockIdx.x;
    const int nt = threadIdx.x >> 6;
    const int l  = threadIdx.x & 63;
    const int col  = nt * 16 + (l & 15);
    const int krow = ks * 32 + ((l >> 4) << 3);
    FragU F0, F1, F2;
#pragma unroll
    for (int j = 0; j < 4; ++j) {
        const float a = W[(size_t)(krow + 2*j    ) * N_EXPERTS + col];
        const float b = W[(size_t)(krow + 2*j + 1) * N_EXPERTS + col];
        const float ra = a - trunc_bf(a),  rb = b - trunc_bf(b);
        const float sa = ra - trunc_bf(ra), sb = rb - trunc_bf(rb);
        F0.u[j] = pack_hi(a,  b);    // bits 1-8
        F1.u[j] = pack_hi(ra, rb);   // bits 9-16
        F2.u[j] = pack_hi(sa, sb);   // bits 17-24 (exact: a = F0+F1+F2)
    }
    const int idx = (ks * 4 + nt) * 64 + l;
    c0[idx] = F0.v; c1[idx] = F1.v; c2[idx] = F2.v;
}

// ---- main: 16 tokens/block, 4 waves K-split, 6-term MFMA, LDS reduce, epilogue
__global__ __launch_bounds__(256, 4)
void dynk_mfma(const float* __restrict__ x,
               const bf16x8* __restrict__ c0, const bf16x8* __restrict__ c1,
               const bf16x8* __restrict__ c2,
               const float* __restrict__ b,
               float* __restrict__ out_rw, float* __restrict__ out_probs,
               float* __restrict__ out_cnt, int n_tok)
{
    __shared__ float red[4 * 16 * 65];
    const int l  = threadIdx.x & 63;
    const int kv = threadIdx.x >> 6;
    const int tok0 = blockIdx.x * 16;
    if (tok0 >= n_tok) return;

    const int r = l & 15;
    const int q = l >> 4;
    const float* xrow = x + (size_t)(tok0 + r) * D_MODEL + q * 8;

    f32x4 acc[4] = {f32x4{0,0,0,0}, f32x4{0,0,0,0}, f32x4{0,0,0,0}, f32x4{0,0,0,0}};

#pragma unroll 4
    for (int s = 0; s < 16; ++s) {
        const int ks = kv * 16 + s;
        const float4 xa = *reinterpret_cast<const float4*>(xrow + ks * 32);
        const float4 xb = *reinterpret_cast<const float4*>(xrow + ks * 32 + 4);
        const float f[8] = {xa.x, xa.y, xa.z, xa.w, xb.x, xb.y, xb.z, xb.w};

        FragU A0, A1, A2;
#pragma unroll
        for (int j = 0; j < 4; ++j) {
            const float p0 = f[2*j], p1 = f[2*j+1];
            const float r0 = p0 - trunc_bf(p0), r1 = p1 - trunc_bf(p1);
            const float s0 = r0 - trunc_bf(r0), s1 = r1 - trunc_bf(r1);
            A0.u[j] = pack_hi(p0, p1);
            A1.u[j] = pack_hi(r0, r1);
            A2.u[j] = pack_hi(s0, s1);
        }

#pragma unroll
        for (int nt = 0; nt < 4; ++nt) {
            const int idx = (ks * 4 + nt) * 64 + l;
            const bf16x8 B0 = c0[idx];
            const bf16x8 B1 = c1[idx];
            const bf16x8 B2 = c2[idx];
            // smallest terms first (order-insurance), all exactly-representable products
            acc[nt] = __builtin_amdgcn_mfma_f32_16x16x32_bf16(A2.v, B0, acc[nt], 0, 0, 0);
            acc[nt] = __builtin_amdgcn_mfma_f32_16x16x32_bf16(A0.v, B2, acc[nt], 0, 0, 0);
            acc[nt] = __builtin_amdgcn_mfma_f32_16x16x32_bf16(A1.v, B1, acc[nt], 0, 0, 0);
            acc[nt] = __builtin_amdgcn_mfma_f32_16x16x32_bf16(A1.v, B0, acc[nt], 0, 0, 0);
            acc[nt] = __builtin_amdgcn_mfma_f32_16x16x32_bf16(A0.v, B1, acc[nt], 0, 0, 0);
            acc[nt] = __builtin_amdgcn_mfma_f32_16x16x32_bf16(A0.v, B0, acc[nt], 0, 0, 0);
        }
    }

    // D layout: col=lane&15, row=(lane>>4)*4+j  (m89-verified, round-3-confirmed)
#pragma unroll
    for (int nt = 0; nt < 4; ++nt)
#pragma unroll
        for (int j = 0; j < 4; ++j)
            red[(kv * 16 + (q * 4 + j)) * 65 + (nt * 16 + r)] = acc[nt][j];
    __syncthreads();

#pragma unroll 1
    for (int t = 0; t < 4; ++t) {
        const int row = kv * 4 + t;
        const long tok = tok0 + row;
        if (tok >= n_tok) break;

        float lg = b[l];
#pragma unroll
        for (int kk = 0; kk < 4; ++kk) lg += red[(kk * 16 + row) * 65 + l];

        float m = lg;
#pragma unroll
        for (int d = 32; d > 0; d >>= 1) m = fmaxf(m, __shfl_xor(m, d));
        const float e = expf(lg - m);
        float sden = e;
#pragma unroll
        for (int d = 32; d > 0; d >>= 1) sden += __shfl_xor(sden, d);
        const float p = e / sden;

        float S = 0.f;
#pragma unroll
        for (int j = 0; j < 64; ++j) {
            const float pj = __shfl(p, j);
            const bool before = (pj > p) || (pj == p && j < l);
            S += before ? pj : 0.f;
        }
        const bool active = (S < THRESH);

        float total = active ? p : 0.f;
#pragma unroll
        for (int d = 32; d > 0; d >>= 1) total += __shfl_xor(total, d);

        const unsigned long long msk = __ballot(active);
        const int cnt = __popcll(msk);
        const float wgt = active ? p / (total + 1e-6f) : 0.f;

        out_rw[tok * N_EXPERTS + l]    = wgt;
        out_probs[tok * N_EXPERTS + l] = p;
        if (l == 0) out_cnt[tok] = (float)cnt;
    }
}

// ---- fallback (round-2 proven fp32 kernel) if workspace is too small
__global__ __launch_bounds__(256, 2)
void dynk_fallback(const float* __restrict__ x, const float* __restrict__ W,
                   const float* __restrict__ b, float* __restrict__ out_rw,
                   float* __restrict__ out_probs, float* __restrict__ out_cnt,
                   int n_tok)
{
    const int lane = threadIdx.x & 63;
    const int wid  = threadIdx.x >> 6;
    const long tok0 = (long)blockIdx.x * 32 + (long)wid * 8;
    if (tok0 >= n_tok) return;
    float acc[8];
    const float bias = b[lane];
#pragma unroll
    for (int t = 0; t < 8; ++t) acc[t] = bias;
    const float* xp = x + tok0 * D_MODEL;
    for (int k0 = 0; k0 < D_MODEL; k0 += 8) {
        float w[8];
#pragma unroll
        for (int j = 0; j < 8; ++j) w[j] = W[(long)(k0 + j) * N_EXPERTS + lane];
#pragma unroll
        for (int t = 0; t < 8; ++t) {
            const float4 xa = *reinterpret_cast<const float4*>(xp + (long)t * D_MODEL + k0);
            const float4 xb = *reinterpret_cast<const float4*>(xp + (long)t * D_MODEL + k0 + 4);
            acc[t] = fmaf(xa.x, w[0], acc[t]); acc[t] = fmaf(xa.y, w[1], acc[t]);
            acc[t] = fmaf(xa.z, w[2], acc[t]); acc[t] = fmaf(xa.w, w[3], acc[t]);
            acc[t] = fmaf(xb.x, w[4], acc[t]); acc[t] = fmaf(xb.y, w[5], acc[t]);
            acc[t] = fmaf(xb.z, w[6], acc[t]); acc[t] = fmaf(xb.w, w[7], acc[t]);
        }
    }
#pragma unroll 1
    for (int t = 0; t < 8; ++t) {
        const long tok = tok0 + t;
        const float lgt = acc[t];
        float m = lgt;
#pragma unroll
        for (int d = 32; d > 0; d >>= 1) m = fmaxf(m, __shfl_xor(m, d));
        const float e = expf(lgt - m);
        float s = e;
#pragma unroll
        for (int d = 32; d > 0; d >>= 1) s += __shfl_xor(s, d);
        const float p = e / s;
        float S = 0.f;
#pragma unroll
        for (int j = 0; j < 64; ++j) {
            const float pj = __shfl(p, j);
            S += ((pj > p) || (pj == p && j < lane)) ? pj : 0.f;
        }
        const bool active = (S < THRESH);
        float total = active ? p : 0.f;
#pragma unroll
        for (int d = 32; d > 0; d >>= 1) total += __shfl_xor(total, d);
        const int cnt = __popcll(__ballot(active));
        const float wgt = active ? p / (total + 1e-6f) : 0.f;
        out_rw[tok * N_EXPERTS + lane]    = wgt;
        out_probs[tok * N_EXPERTS + lane] = p;
        if (lane == 0) out_cnt[tok] = (float)cnt;
    }
}

extern "C" void kernel_launch(void* const* d_in, const int* in_sizes, int n_in,
                              void* d_out, int out_size, void* d_ws, size_t ws_size,
                              hipStream_t stream) {
    const float* x = (const float*)d_in[0];
    const float* W = (const float*)d_in[1];
    const float* b = (const float*)d_in[2];
    const int n_tok = in_sizes[0] / D_MODEL;

    float* out   = (float*)d_out;
    float* rw    = out;
    float* probs = out + (size_t)n_tok * N_EXPERTS;
    float* cnt   = out + 2 * (size_t)n_tok * N_EXPERTS;

    const size_t frag_elems = 64 * 4 * 64;           // per split level
    const size_t need = 3 * frag_elems * sizeof(bf16x8);  // 768 KB

    if (ws_size < need) {
        const int blocks = (n_tok + 31) / 32;
        dynk_fallback<<<blocks, 256, 0, stream>>>(x, W, b, rw, probs, cnt, n_tok);
        return;
    }

    bf16x8* c0 = (bf16x8*)d_ws;
    bf16x8* c1 = c0 + frag_elems;
    bf16x8* c2 = c1 + frag_elems;

    prepack_w<<<64, 256, 0, stream>>>(W, c0, c1, c2);

    const int blocks = (n_tok + 15) / 16;
    dynk_mfma<<<blocks, 256, 0, stream>>>(x, c0, c1, c2, b, rw, probs, cnt, n_tok);
}

// Round 6
// 224.061 us; speedup vs baseline: 2.3664x; 1.0702x over previous
//
#include <hip/hip_runtime.h>

#define D_MODEL   2048
#define N_EXPERTS 64
#define THRESH    0.9f
#define TOK_BLK   16
#define KV_WAVES  16   // K-split across 16 waves (1024-thread block)

typedef __attribute__((ext_vector_type(8))) short bf16x8;
typedef __attribute__((ext_vector_type(4))) float f32x4;

union FragU { unsigned u[4]; bf16x8 v; };

// pack {top16(f0) low, top16(f1) high}
__device__ __forceinline__ unsigned pack_hi(float f0, float f1) {
    return __builtin_amdgcn_perm(__float_as_uint(f1), __float_as_uint(f0), 0x07060302u);
}
__device__ __forceinline__ float trunc_bf(float f) {
    return __uint_as_float(__float_as_uint(f) & 0xFFFF0000u);
}

// ---- prepack W [2048][64] fp32 -> EXACT 3-way bf16 split fragments in d_ws
__global__ void prepack_w(const float* __restrict__ W,
                          bf16x8* __restrict__ c0, bf16x8* __restrict__ c1,
                          bf16x8* __restrict__ c2)
{
    const int ks = blockIdx.x;
    const int nt = threadIdx.x >> 6;
    const int l  = threadIdx.x & 63;
    const int col  = nt * 16 + (l & 15);
    const int krow = ks * 32 + ((l >> 4) << 3);
    FragU F0, F1, F2;
#pragma unroll
    for (int j = 0; j < 4; ++j) {
        const float a = W[(size_t)(krow + 2*j    ) * N_EXPERTS + col];
        const float b = W[(size_t)(krow + 2*j + 1) * N_EXPERTS + col];
        const float ra = a - trunc_bf(a),  rb = b - trunc_bf(b);
        const float sa = ra - trunc_bf(ra), sb = rb - trunc_bf(rb);
        F0.u[j] = pack_hi(a,  b);
        F1.u[j] = pack_hi(ra, rb);
        F2.u[j] = pack_hi(sa, sb);   // exact: a = F0+F1+F2
    }
    const int idx = (ks * 4 + nt) * 64 + l;
    c0[idx] = F0.v; c1[idx] = F1.v; c2[idx] = F2.v;
}

// ---- main: 16 tokens/block, 16 waves K-split, 6-term MFMA, LDS reduce, epilogue
__global__ __launch_bounds__(1024, 8)
void dynk_mfma(const float* __restrict__ x,
               const bf16x8* __restrict__ c0, const bf16x8* __restrict__ c1,
               const bf16x8* __restrict__ c2,
               const float* __restrict__ b,
               float* __restrict__ out_rw, float* __restrict__ out_probs,
               float* __restrict__ out_cnt, int n_tok)
{
    __shared__ float red[KV_WAVES * 16 * 64];   // exactly 64 KB, no pad
    const int l  = threadIdx.x & 63;
    const int kv = threadIdx.x >> 6;            // wave id = K sixteenth
    const int tok0 = blockIdx.x * TOK_BLK;

    const int r = l & 15;                       // A row / B col within tile
    const int q = l >> 4;                       // k sub-block
    int xr = tok0 + r; if (xr >= n_tok) xr = n_tok - 1;   // tail-safe
    const float* xrow = x + (size_t)xr * D_MODEL + q * 8;

    f32x4 acc[4] = {f32x4{0,0,0,0}, f32x4{0,0,0,0}, f32x4{0,0,0,0}, f32x4{0,0,0,0}};

#pragma unroll
    for (int s = 0; s < 4; ++s) {
        const int ks = kv * 4 + s;              // absolute k-step (32 elems)
        const float4 xa = *reinterpret_cast<const float4*>(xrow + ks * 32);
        const float4 xb = *reinterpret_cast<const float4*>(xrow + ks * 32 + 4);
        const float f[8] = {xa.x, xa.y, xa.z, xa.w, xb.x, xb.y, xb.z, xb.w};

        FragU A0, A1, A2;
#pragma unroll
        for (int j = 0; j < 4; ++j) {
            const float p0 = f[2*j], p1 = f[2*j+1];
            const float r0 = p0 - trunc_bf(p0), r1 = p1 - trunc_bf(p1);
            const float s0 = r0 - trunc_bf(r0), s1 = r1 - trunc_bf(r1);
            A0.u[j] = pack_hi(p0, p1);
            A1.u[j] = pack_hi(r0, r1);
            A2.u[j] = pack_hi(s0, s1);
        }

#pragma unroll
        for (int nt = 0; nt < 4; ++nt) {
            const int idx = (ks * 4 + nt) * 64 + l;
            const bf16x8 B0 = c0[idx];
            const bf16x8 B1 = c1[idx];
            const bf16x8 B2 = c2[idx];
            acc[nt] = __builtin_amdgcn_mfma_f32_16x16x32_bf16(A2.v, B0, acc[nt], 0, 0, 0);
            acc[nt] = __builtin_amdgcn_mfma_f32_16x16x32_bf16(A0.v, B2, acc[nt], 0, 0, 0);
            acc[nt] = __builtin_amdgcn_mfma_f32_16x16x32_bf16(A1.v, B1, acc[nt], 0, 0, 0);
            acc[nt] = __builtin_amdgcn_mfma_f32_16x16x32_bf16(A1.v, B0, acc[nt], 0, 0, 0);
            acc[nt] = __builtin_amdgcn_mfma_f32_16x16x32_bf16(A0.v, B1, acc[nt], 0, 0, 0);
            acc[nt] = __builtin_amdgcn_mfma_f32_16x16x32_bf16(A0.v, B0, acc[nt], 0, 0, 0);
        }
    }

    // D layout: col=lane&15, row=(lane>>4)*4+j  (verified rounds 3/4)
#pragma unroll
    for (int nt = 0; nt < 4; ++nt)
#pragma unroll
        for (int j = 0; j < 4; ++j)
            red[(kv * 16 + q * 4 + j) * 64 + (nt * 16 + r)] = acc[nt][j];
    __syncthreads();

    // epilogue: wave kv owns token row kv; lane = expert
    const long tok = (long)tok0 + kv;
    if (tok < n_tok) {
        float lg = b[l];
#pragma unroll
        for (int kk = 0; kk < KV_WAVES; ++kk) lg += red[(kk * 16 + kv) * 64 + l];

        float m = lg;
#pragma unroll
        for (int d = 32; d > 0; d >>= 1) m = fmaxf(m, __shfl_xor(m, d));
        const float e = expf(lg - m);
        float sden = e;
#pragma unroll
        for (int d = 32; d > 0; d >>= 1) sden += __shfl_xor(sden, d);
        const float p = e / sden;

        // mass of experts ranked strictly before this lane (stable ties by index)
        float S = 0.f;
#pragma unroll
        for (int j = 0; j < 64; ++j) {
            const float pj = __shfl(p, j);
            const bool before = (pj > p) || (pj == p && j < l);
            S += before ? pj : 0.f;
        }
        const bool active = (S < THRESH);

        float total = active ? p : 0.f;
#pragma unroll
        for (int d = 32; d > 0; d >>= 1) total += __shfl_xor(total, d);

        const int cnt = __popcll(__ballot(active));
        const float wgt = active ? p / (total + 1e-6f) : 0.f;

        out_rw[tok * N_EXPERTS + l]    = wgt;
        out_probs[tok * N_EXPERTS + l] = p;
        if (l == 0) out_cnt[tok] = (float)cnt;
    }
}

// ---- fallback (round-2 proven fp32 kernel) if workspace is too small
__global__ __launch_bounds__(256, 2)
void dynk_fallback(const float* __restrict__ x, const float* __restrict__ W,
                   const float* __restrict__ b, float* __restrict__ out_rw,
                   float* __restrict__ out_probs, float* __restrict__ out_cnt,
                   int n_tok)
{
    const int lane = threadIdx.x & 63;
    const int wid  = threadIdx.x >> 6;
    const long tok0 = (long)blockIdx.x * 32 + (long)wid * 8;
    if (tok0 >= n_tok) return;
    float acc[8];
    const float bias = b[lane];
#pragma unroll
    for (int t = 0; t < 8; ++t) acc[t] = bias;
    const float* xp = x + tok0 * D_MODEL;
    for (int k0 = 0; k0 < D_MODEL; k0 += 8) {
        float w[8];
#pragma unroll
        for (int j = 0; j < 8; ++j) w[j] = W[(long)(k0 + j) * N_EXPERTS + lane];
#pragma unroll
        for (int t = 0; t < 8; ++t) {
            const float4 xa = *reinterpret_cast<const float4*>(xp + (long)t * D_MODEL + k0);
            const float4 xb = *reinterpret_cast<const float4*>(xp + (long)t * D_MODEL + k0 + 4);
            acc[t] = fmaf(xa.x, w[0], acc[t]); acc[t] = fmaf(xa.y, w[1], acc[t]);
            acc[t] = fmaf(xa.z, w[2], acc[t]); acc[t] = fmaf(xa.w, w[3], acc[t]);
            acc[t] = fmaf(xb.x, w[4], acc[t]); acc[t] = fmaf(xb.y, w[5], acc[t]);
            acc[t] = fmaf(xb.z, w[6], acc[t]); acc[t] = fmaf(xb.w, w[7], acc[t]);
        }
    }
#pragma unroll 1
    for (int t = 0; t < 8; ++t) {
        const long tok = tok0 + t;
        const float lgt = acc[t];
        float m = lgt;
#pragma unroll
        for (int d = 32; d > 0; d >>= 1) m = fmaxf(m, __shfl_xor(m, d));
        const float e = expf(lgt - m);
        float s = e;
#pragma unroll
        for (int d = 32; d > 0; d >>= 1) s += __shfl_xor(s, d);
        const float p = e / s;
        float S = 0.f;
#pragma unroll
        for (int j = 0; j < 64; ++j) {
            const float pj = __shfl(p, j);
            S += ((pj > p) || (pj == p && j < lane)) ? pj : 0.f;
        }
        const bool active = (S < THRESH);
        float total = active ? p : 0.f;
#pragma unroll
        for (int d = 32; d > 0; d >>= 1) total += __shfl_xor(total, d);
        const int cnt = __popcll(__ballot(active));
        const float wgt = active ? p / (total + 1e-6f) : 0.f;
        out_rw[tok * N_EXPERTS + lane]    = wgt;
        out_probs[tok * N_EXPERTS + lane] = p;
        if (lane == 0) out_cnt[tok] = (float)cnt;
    }
}

extern "C" void kernel_launch(void* const* d_in, const int* in_sizes, int n_in,
                              void* d_out, int out_size, void* d_ws, size_t ws_size,
                              hipStream_t stream) {
    const float* x = (const float*)d_in[0];
    const float* W = (const float*)d_in[1];
    const float* b = (const float*)d_in[2];
    const int n_tok = in_sizes[0] / D_MODEL;

    float* out   = (float*)d_out;
    float* rw    = out;
    float* probs = out + (size_t)n_tok * N_EXPERTS;
    float* cnt   = out + 2 * (size_t)n_tok * N_EXPERTS;

    const size_t frag_elems = 64 * 4 * 64;                // per split level
    const size_t need = 3 * frag_elems * sizeof(bf16x8);  // 768 KB

    if (ws_size < need) {
        const int blocks = (n_tok + 31) / 32;
        dynk_fallback<<<blocks, 256, 0, stream>>>(x, W, b, rw, probs, cnt, n_tok);
        return;
    }

    bf16x8* c0 = (bf16x8*)d_ws;
    bf16x8* c1 = c0 + frag_elems;
    bf16x8* c2 = c1 + frag_elems;

    prepack_w<<<64, 256, 0, stream>>>(W, c0, c1, c2);

    const int blocks = (n_tok + TOK_BLK - 1) / TOK_BLK;
    dynk_mfma<<<blocks, 1024, 0, stream>>>(x, c0, c1, c2, b, rw, probs, cnt, n_tok);
}